// Round 1
// baseline (265.709 us; speedup 1.0000x reference)
//
#include <hip/hip_runtime.h>

// ============================================================================
// FusedConv: per-edge MLP (32->256->256->768-slice) + small tensor contraction.
// Strategy: bf16 MFMA (16x16x32) for the three GEMMs, fp32 accumulate,
// everything fused per 32-edge tile through LDS. Weights pre-transposed to
// n-major bf16 in ws so B-fragments are 16B-contiguous per lane.
// E=65536, block=256 thr (4 waves), 32 edges/block -> 2048 blocks.
// LDS: h1(16K, xor-swizzled) + h2(16K) + rp scratch(12.5K) = 45.6KB -> 3 blk/CU.
// ============================================================================

typedef __bf16 bf16x8 __attribute__((ext_vector_type(8)));
typedef float f32x4 __attribute__((ext_vector_type(4)));

#define TE 32
#define E_TOT 65536

__device__ __forceinline__ f32x4 mfma16(bf16x8 a, bf16x8 b, f32x4 c) {
    return __builtin_amdgcn_mfma_f32_16x16x32_bf16(a, b, c, 0, 0, 0);
}

__device__ __forceinline__ float gelu_f(float x) {
    return 0.5f * x * (1.0f + erff(x * 0.7071067811865476f));
}

// ---- ws layout (bytes) ----
#define WS_W1T   0u         // 256 x 32  bf16 (n-major)   16384 B
#define WS_W2T   16384u     // 256 x 256 bf16 (n-major)  131072 B
#define WS_W3KT  147456u    // 768 x 256 bf16 (n-major)  393216 B
#define WS_EBF   540672u    // E x 32 bf16               4194304 B

#define N_W1T  8192
#define N_W2T  65536
#define N_W3KT 196608
#define N_EBF  2097152
#define PREP_TOT (N_W1T + N_W2T + N_W3KT + N_EBF)

__global__ __launch_bounds__(256) void prep_kernel(
    const float* __restrict__ edges, const float* __restrict__ W1,
    const float* __restrict__ W2, const float* __restrict__ W3,
    __bf16* __restrict__ W1T, __bf16* __restrict__ W2T,
    __bf16* __restrict__ W3kT, __bf16* __restrict__ ebf)
{
    int stride = gridDim.x * blockDim.x;
    for (int idx = blockIdx.x * blockDim.x + threadIdx.x; idx < PREP_TOT; idx += stride) {
        if (idx < N_W1T) {
            int n = idx >> 5, k = idx & 31;
            W1T[idx] = (__bf16)W1[k * 256 + n];
        } else if (idx < N_W1T + N_W2T) {
            int t = idx - N_W1T; int n = t >> 8, k = t & 255;
            W2T[t] = (__bf16)W2[k * 256 + n];
        } else if (idx < N_W1T + N_W2T + N_W3KT) {
            int t = idx - (N_W1T + N_W2T); int n = t >> 8, k = t & 255;
            W3kT[t] = (__bf16)W3[k * 1536 + 768 + n];
        } else {
            int t = idx - (N_W1T + N_W2T + N_W3KT);
            ebf[t] = (__bf16)edges[t];
        }
    }
}

// A-frag layout: lane holds A[m=lane&15][k=(lane>>4)*8 + j], j=0..7
// B-frag layout: lane holds B[k=(lane>>4)*8 + j][n=lane&15]
// C/D layout:    element (row=(lane>>4)*4 + reg, col=lane&15)
__global__ __launch_bounds__(256) void fused_kernel(
    const __bf16* __restrict__ ebf, const __bf16* __restrict__ W1T,
    const __bf16* __restrict__ W2T, const __bf16* __restrict__ W3kT,
    const float* __restrict__ b1, const float* __restrict__ b2,
    const float* __restrict__ feats, const float* __restrict__ basis,
    float* __restrict__ out)
{
    __shared__ __align__(16) unsigned char smem[45568];
    unsigned char* h1s = smem;              // 16384 B (32 rows x 512 B, xor-swizzled 16B chunks)
    unsigned char* h2s = smem + 16384;      // 16384 B
    unsigned char* rps = smem + 32768;      // 4 waves x 32 x 50 bf16 = 12800 B
    __bf16* tmpT   = (__bf16*)smem;         // 3*48*32 bf16 = 9216 B (reuses h1 area after G2)
    __bf16* featsb = (__bf16*)(smem + 9216);  // 32*48 bf16 = 3072 B
    __bf16* basisb = (__bf16*)(smem + 12288); // 32*27 bf16 = 1728 B

    const int tid = threadIdx.x;
    const int w = tid >> 6;       // wave 0..3
    const int l = tid & 63;
    const int c = l & 15;
    const int q = l >> 4;         // 0..3
    const int eb = blockIdx.x * TE;

    const f32x4 zero = {0.f, 0.f, 0.f, 0.f};

    // ---------------- G1: h1 = gelu(edges @ W1 + b1), K=32 (one MFMA step) ---
    bf16x8 a0 = *(const bf16x8*)(ebf + (unsigned)(eb + c) * 32 + q * 8);
    bf16x8 a1 = *(const bf16x8*)(ebf + (unsigned)(eb + 16 + c) * 32 + q * 8);
    f32x4 acc1[2][4];
    #pragma unroll
    for (int mt = 0; mt < 2; ++mt)
        #pragma unroll
        for (int nt = 0; nt < 4; ++nt) acc1[mt][nt] = zero;

    #pragma unroll
    for (int nt = 0; nt < 4; ++nt) {
        int col = w * 64 + nt * 16 + c;
        bf16x8 bf = *(const bf16x8*)(W1T + col * 32 + q * 8);
        acc1[0][nt] = mfma16(a0, bf, acc1[0][nt]);
        acc1[1][nt] = mfma16(a1, bf, acc1[1][nt]);
    }
    #pragma unroll
    for (int nt = 0; nt < 4; ++nt) {
        int col = w * 64 + nt * 16 + c;
        float bias = b1[col];
        #pragma unroll
        for (int mt = 0; mt < 2; ++mt)
            #pragma unroll
            for (int r = 0; r < 4; ++r) {
                int e = mt * 16 + q * 4 + r;
                float g = gelu_f(acc1[mt][nt][r] + bias);
                int chunk = (col >> 3) ^ (e & 7);
                *(__bf16*)(h1s + e * 512 + chunk * 16 + (col & 7) * 2) = (__bf16)g;
            }
    }
    __syncthreads();

    // ---------------- G2: h2 = gelu(h1 @ W2 + b2), K=256 -------------------
    f32x4 acc2[2][4];
    #pragma unroll
    for (int mt = 0; mt < 2; ++mt)
        #pragma unroll
        for (int nt = 0; nt < 4; ++nt) acc2[mt][nt] = zero;

    #pragma unroll
    for (int ks = 0; ks < 8; ++ks) {
        bf16x8 af[2];
        #pragma unroll
        for (int mt = 0; mt < 2; ++mt) {
            int m = mt * 16 + c;
            int chunk = (ks * 4 + q) ^ (m & 7);
            af[mt] = *(const bf16x8*)(h1s + m * 512 + chunk * 16);
        }
        #pragma unroll
        for (int nt = 0; nt < 4; ++nt) {
            int col = w * 64 + nt * 16 + c;
            bf16x8 bf = *(const bf16x8*)(W2T + col * 256 + ks * 32 + q * 8);
            acc2[0][nt] = mfma16(af[0], bf, acc2[0][nt]);
            acc2[1][nt] = mfma16(af[1], bf, acc2[1][nt]);
        }
    }
    #pragma unroll
    for (int nt = 0; nt < 4; ++nt) {
        int col = w * 64 + nt * 16 + c;
        float bias = b2[col];
        #pragma unroll
        for (int mt = 0; mt < 2; ++mt)
            #pragma unroll
            for (int r = 0; r < 4; ++r) {
                int e = mt * 16 + q * 4 + r;
                float g = gelu_f(acc2[mt][nt][r] + bias);
                int chunk = (col >> 3) ^ (e & 7);
                *(__bf16*)(h2s + e * 512 + chunk * 16 + (col & 7) * 2) = (__bf16)g;
            }
    }
    __syncthreads();

    // ------- stage feats/basis (bf16) and build tmpT[d][J][e] in h1 area ----
    for (int i = tid; i < TE * 48; i += 256)
        featsb[i] = (__bf16)feats[(unsigned)eb * 48 + i];
    for (int i = tid; i < TE * 27; i += 256)
        basisb[i] = (__bf16)basis[(unsigned)eb * 27 + i];
    __syncthreads();
    for (int f = tid; f < 3 * 48 * TE; f += 256) {
        int e = f & 31;
        int t = f >> 5;
        int J = t % 48;        // J = 3*i + nf
        int d = t / 48;
        int i0 = J / 3, nf = J % 3;
        float s = 0.f;
        #pragma unroll
        for (int c2 = 0; c2 < 3; ++c2)
            s += (float)featsb[e * 48 + i0 * 3 + c2] *
                 (float)basisb[e * 27 + c2 * 9 + nf * 3 + d];
        tmpT[f] = (__bf16)s;
    }
    __syncthreads();

    // ------- G3 (rp = h2 @ W3k) fused with final contraction, per o ----------
    for (int oi = 0; oi < 4; ++oi) {
        int o = w * 4 + oi;          // wave owns o's {4w..4w+3}
        f32x4 acc3[2][3];
        #pragma unroll
        for (int mt = 0; mt < 2; ++mt)
            #pragma unroll
            for (int nt = 0; nt < 3; ++nt) acc3[mt][nt] = zero;

        #pragma unroll
        for (int ks = 0; ks < 8; ++ks) {
            bf16x8 af[2];
            #pragma unroll
            for (int mt = 0; mt < 2; ++mt) {
                int m = mt * 16 + c;
                int chunk = (ks * 4 + q) ^ (m & 7);
                af[mt] = *(const bf16x8*)(h2s + m * 512 + chunk * 16);
            }
            #pragma unroll
            for (int nt = 0; nt < 3; ++nt) {
                int col = o * 48 + nt * 16 + c;
                bf16x8 bf = *(const bf16x8*)(W3kT + col * 256 + ks * 32 + q * 8);
                acc3[0][nt] = mfma16(af[0], bf, acc3[0][nt]);
                acc3[1][nt] = mfma16(af[1], bf, acc3[1][nt]);
            }
        }
        // drop this o-chunk (32 edges x 48 cols) to per-wave LDS scratch
        unsigned char* rpw = rps + w * 3200;
        #pragma unroll
        for (int nt = 0; nt < 3; ++nt)
            #pragma unroll
            for (int mt = 0; mt < 2; ++mt)
                #pragma unroll
                for (int r = 0; r < 4; ++r) {
                    int e = mt * 16 + q * 4 + r;
                    int J = nt * 16 + c;
                    *(__bf16*)(rpw + e * 100 + J * 2) = (__bf16)acc3[mt][nt][r];
                }
        __syncthreads();

        // out[e][o][d] = sum_J rp[e][J] * tmpT[d][J][e]; 2 lanes per edge
        int e = l & 31, hv = l >> 5;
        const unsigned char* rpr = rps + w * 3200 + e * 100;
        float p0 = 0.f, p1 = 0.f, p2 = 0.f;
        #pragma unroll
        for (int jj = 0; jj < 24; ++jj) {
            int J = hv * 24 + jj;
            float rv = (float)*(const __bf16*)(rpr + J * 2);
            p0 += rv * (float)tmpT[J * 32 + e];
            p1 += rv * (float)tmpT[(48 + J) * 32 + e];
            p2 += rv * (float)tmpT[(96 + J) * 32 + e];
        }
        p0 += __shfl_xor(p0, 32, 64);
        p1 += __shfl_xor(p1, 32, 64);
        p2 += __shfl_xor(p2, 32, 64);
        if (hv == 0) {
            float* op = out + (unsigned)(eb + e) * 48 + o * 3;
            op[0] = p0; op[1] = p1; op[2] = p2;
        }
        __syncthreads();
    }
}

extern "C" void kernel_launch(void* const* d_in, const int* in_sizes, int n_in,
                              void* d_out, int out_size, void* d_ws, size_t ws_size,
                              hipStream_t stream) {
    const float* edges = (const float*)d_in[0];
    const float* feats = (const float*)d_in[1];
    const float* basis = (const float*)d_in[2];
    const float* W1    = (const float*)d_in[3];
    const float* b1    = (const float*)d_in[4];
    const float* W2    = (const float*)d_in[5];
    const float* b2    = (const float*)d_in[6];
    const float* W3    = (const float*)d_in[7];
    float* out = (float*)d_out;

    __bf16* W1T  = (__bf16*)((char*)d_ws + WS_W1T);
    __bf16* W2T  = (__bf16*)((char*)d_ws + WS_W2T);
    __bf16* W3kT = (__bf16*)((char*)d_ws + WS_W3KT);
    __bf16* ebf  = (__bf16*)((char*)d_ws + WS_EBF);

    prep_kernel<<<1024, 256, 0, stream>>>(edges, W1, W2, W3, W1T, W2T, W3kT, ebf);
    fused_kernel<<<E_TOT / TE, 256, 0, stream>>>(ebf, W1T, W2T, W3kT, b1, b2,
                                                 feats, basis, out);
}